// Round 9
// baseline (705.791 us; speedup 1.0000x reference)
//
#include <hip/hip_runtime.h>
#include <hip/hip_bf16.h>
#include <math.h>

// Problem constants (fixed by reference): N=100000 nodes, E=1.6M edges, H=256, T=64.

static inline size_t align512(size_t x){ return (x + 511) & ~size_t(511); }

typedef _Float16 h2_t __attribute__((ext_vector_type(2)));
typedef unsigned short ushort_t;
typedef short bf16x8 __attribute__((ext_vector_type(8)));   // 8 bf16 = 4 VGPRs (MFMA A/B frag)
typedef float f32x4 __attribute__((ext_vector_type(4)));    // MFMA C/D frag
typedef float f32x2 __attribute__((ext_vector_type(2)));

#if defined(__has_builtin)
#if __has_builtin(__builtin_amdgcn_fdot2)
#define HAS_FDOT2 1
#endif
#if __has_builtin(__builtin_amdgcn_cvt_pk_f32_fp8) && __has_builtin(__builtin_amdgcn_cvt_pk_fp8_f32)
#define HAS_FP8CVT 1
#endif
#endif

__device__ inline ushort_t f2bf(float f){
  unsigned u = __float_as_uint(f);
  unsigned r = u + 0x7FFFu + ((u >> 16) & 1u);   // RTNE
  return (ushort_t)(r >> 16);
}
__device__ inline float bf2f(ushort_t h){ return __uint_as_float(((unsigned)h) << 16); }
__device__ inline unsigned pk2bf(float lo, float hi){
  return ((unsigned)f2bf(hi) << 16) | (unsigned)f2bf(lo);
}
__device__ inline bf16x8 as_bf16x8(uint4 u){
  union { uint4 u4; bf16x8 b; } c; c.u4 = u; return c.b;
}
__device__ inline h2_t u2h2(unsigned u){
  union { unsigned u; h2_t h; } c; c.u = u; return c.h;
}
__device__ inline float fdot2a(h2_t a, h2_t b, float c){
#ifdef HAS_FDOT2
  return __builtin_amdgcn_fdot2(a, b, c, false);
#else
  return fmaf((float)a.x, (float)b.x, fmaf((float)a.y, (float)b.y, c));
#endif
}

// ---- fp8 e4m3 encode/decode (HW cvt on gfx950; SW fallback approximate) ----

__device__ inline unsigned char f2fp8(float x){
#ifdef HAS_FP8CVT
  int p = __builtin_amdgcn_cvt_pk_fp8_f32(x, x, 0, false);
  return (unsigned char)(p & 0xFF);
#else
  unsigned u = __float_as_uint(x);
  unsigned s = (u >> 24) & 0x80u;
  unsigned um = u & 0x7FFFFFFFu;
  if (um >= 0x43E00000u) return (unsigned char)(s | 0x7E);      // clamp to 448
  if (um <  0x3C000000u) return (unsigned char)s;               // flush < 2^-7
  unsigned r = um + 0x7FFFFu + ((um >> 20) & 1u);               // RTNE at bit 20
  unsigned e = (r >> 23) & 0xFF, m = (r >> 20) & 7u;
  return (unsigned char)(s | ((e - 120u) << 3) | m);
#endif
}
__device__ inline void fp8x4_to_f32(unsigned v, float& a, float& b, float& c, float& d){
#ifdef HAS_FP8CVT
  f32x2 lo = __builtin_amdgcn_cvt_pk_f32_fp8(v, false);
  f32x2 hi = __builtin_amdgcn_cvt_pk_f32_fp8(v, true);
  a = lo.x; b = lo.y; c = hi.x; d = hi.y;
#else
  auto d1 = [](unsigned char t)->float{
    unsigned s = (t >> 7) & 1u, e = (t >> 3) & 0xFu, m = t & 7u;
    float v = (e == 0) ? ldexpf((float)m, -9) : ldexpf(8.0f + (float)m, (int)e - 10);
    return s ? -v : v;
  };
  a = d1(v & 0xFF); b = d1((v >> 8) & 0xFF); c = d1((v >> 16) & 0xFF); d = d1(v >> 24);
#endif
}

// ---------- CSR build ----------

__global__ void count_kernel(const int* __restrict__ ei, int* __restrict__ cnt, int E){
  int e = blockIdx.x*256 + threadIdx.x;
  if (e < E) atomicAdd(&cnt[ei[E + e]], 1);
}

__global__ void dis_kernel(const int* __restrict__ cnt, float* __restrict__ dis, int N){
  int i = blockIdx.x*256 + threadIdx.x;
  if (i < N) dis[i] = rsqrtf((float)cnt[i] + 1.0f);
}

__global__ void scan_block_kernel(const int* __restrict__ cnt, int* __restrict__ rp,
                                  int* __restrict__ bsum, int N){
  __shared__ int s[2][1024];
  int t = threadIdx.x; int i = blockIdx.x*1024 + t;
  int v = (i < N) ? cnt[i] : 0;
  int cur = 0; s[0][t] = v; __syncthreads();
  for (int off = 1; off < 1024; off <<= 1){
    int nxt = cur ^ 1;
    int val = s[cur][t];
    if (t >= off) val += s[cur][t - off];
    s[nxt][t] = val; cur = nxt; __syncthreads();
  }
  if (i < N) rp[i+1] = s[cur][t];
  if (t == 1023) bsum[blockIdx.x] = s[cur][1023];
}

__global__ void scan_sums_kernel(int* __restrict__ bsum, int nb){
  __shared__ int s[128];
  int t = threadIdx.x;
  if (t < nb) s[t] = bsum[t];
  __syncthreads();
  if (t == 0){ int acc = 0; for (int b = 0; b < nb; b++){ int v = s[b]; s[b] = acc; acc += v; } }
  __syncthreads();
  if (t < nb) bsum[t] = s[t];
}

__global__ void add_off_kernel(int* __restrict__ rp, const int* __restrict__ bsum,
                               int* __restrict__ cnt, int N){
  int i = blockIdx.x*256 + threadIdx.x;
  if (i < N){ rp[i+1] += bsum[i >> 10]; cnt[i] = 0; }
  if (i == 0) rp[0] = 0;
}

// fill: pass-major dst-range clustering. Random 4B scatters over the full
// 6.4MB csrc window caused 107MB of write amplification (measured r6:
// 113us, WRITE=107MB). 4 passes shrink the active write window to 1.6MB
// (L2-resident -> ~16 writes accumulate per line before writeback), at the
// cost of reading ei 4x coalesced (51MB ~ 9us). (r7: fill left the top-5.)
#define FILL_P 4

__global__ void fill_kernel(const int* __restrict__ ei, const int* __restrict__ rp,
                            int* __restrict__ cnt, int* __restrict__ csrc, int E, int N){
  int nbp = gridDim.x / FILL_P;
  int pass = blockIdx.x / nbp;
  int blk  = blockIdx.x - pass*nbp;
  int span = (N + FILL_P - 1) / FILL_P;
  int lo = pass*span;
  int hi = min(lo + span, N);
  int e = blk*256 + threadIdx.x;
  if (e < E){
    int d = ei[E + e];
    int s = ei[e];
    if (d >= lo && d < hi){
      int pos = rp[d] + atomicAdd(&cnt[d], 1);
      csrc[pos] = s;
    }
  }
}

// ---------- pack W (256x256 fp32 [k][n]) into MFMA B-fragment order (bf16) ----------

__global__ void packW_kernel(const float* __restrict__ W, uint4* __restrict__ Wp){
  int idx = blockIdx.x*256 + threadIdx.x;    // 0..8191
  int lane = idx & 63;
  int blk  = idx >> 6;                        // 0..127
  int q    = blk & 7;
  int t16  = blk >> 3;                        // 0..15 (16-col group)
  int n = t16*16 + (lane & 15);
  int k = q*32 + (lane >> 4)*8;
  uint4 v;
  v.x = pk2bf(W[(size_t)(k+0)*256 + n], W[(size_t)(k+1)*256 + n]);
  v.y = pk2bf(W[(size_t)(k+2)*256 + n], W[(size_t)(k+3)*256 + n]);
  v.z = pk2bf(W[(size_t)(k+4)*256 + n], W[(size_t)(k+5)*256 + n]);
  v.w = pk2bf(W[(size_t)(k+6)*256 + n], W[(size_t)(k+7)*256 + n]);
  Wp[idx] = v;
}

// ---------- pack W_hh (768x256 f32) into 3-tier GRU layout (f16 h2 units) ----
// Thread t=(i,half) of the 512-thread GRU owns, per gate g in {r,z,n}, the 64
// h2 values hk = half*64 + c*8 + j (c=chunk 0..7, j=0..7) of row i+g*256.
// Regions: REG-layout 88 h2 = r(all 64) + z(c0..2)  [kernel pins words 0..19
// in VGPRs and STREAMS words 20..21 (z c2) per step];  LDS 72 h2 =
// z(c3..7)=40 + n(c0..3)=32;  STREAM 32 h2 = n(c4..7), replicated x2 so the
// per-step reload address alternates with t&1 (blocks LICM reg-hoisting).
// Layouts (unsigned=1 h2):  REG:  [22][512] uint4, slot s -> word s>>2, comp s&3
//                           LDS:  [36][512] uint2, item li -> pair li>>1, comp li&1
//                           STRM: [2][8][512] uint4, item si -> grp si>>2, comp si&3
#define WHHP_LBASE 45056u
#define WHHP_SBASE 81920u
#define WHHP_SREP  16384u
#define WHHP_TOTAL 114688u

__global__ void packWhh_kernel(const float* __restrict__ whh, unsigned* __restrict__ wp){
  int idx = blockIdx.x*256 + threadIdx.x;        // 0..98303
  if (idx >= 98304) return;
  int t = idx / 192;
  int m = idx - t*192;
  int i = t >> 1, half = t & 1;
  int g  = m >> 6;            // 0=r,1=z,2=n
  int mg = m & 63;
  int c = mg >> 3, j = mg & 7;
  int hk = half*64 + c*8 + j;
  int row = i + g*256;
  float a = whh[(size_t)row*256 + 2*hk];
  float b = whh[(size_t)row*256 + 2*hk + 1];
  union { _Float16 f[2]; unsigned u; } cv;
  cv.f[0] = (_Float16)a; cv.f[1] = (_Float16)b;
  if (g == 0){
    int s = c*8 + j;
    wp[(unsigned)((s >> 2)*2048 + t*4 + (s & 3))] = cv.u;
  } else if (g == 1 && c < 3){
    int s = 64 + c*8 + j;
    wp[(unsigned)((s >> 2)*2048 + t*4 + (s & 3))] = cv.u;
  } else if (g == 1){
    int li = (c-3)*8 + j;
    wp[WHHP_LBASE + (unsigned)((li >> 1)*1024 + t*2 + (li & 1))] = cv.u;
  } else if (c < 4){
    int li = 40 + c*8 + j;
    wp[WHHP_LBASE + (unsigned)((li >> 1)*1024 + t*2 + (li & 1))] = cv.u;
  } else {
    int si = (c-4)*8 + j;
    unsigned so = (unsigned)((si >> 2)*2048 + t*4 + (si & 3));
    wp[WHHP_SBASE + so] = cv.u;
    wp[WHHP_SBASE + WHHP_SREP + so] = cv.u;
  }
}

// ---------- MFMA GEMM: out[N,256](fp8 e4m3) = A[N,256] @ W[256,256] ----------
// 128x128 tile, 4 waves (2x2), each wave 64x64 via 4x4 tiles of 16x16x32 MFMA.
// B register-resident (128 VGPRs). A double-buffered in LDS. Out stored fp8
// (the consumer is the edge-gather, which is fabric-bytes-bound).

template<bool A_BF16>
__global__ __launch_bounds__(256, 2) void gemm_mfma(const void* __restrict__ Ap,
                                                    const uint4* __restrict__ Wp,
                                                    unsigned char* __restrict__ out, int N){
  __shared__ __align__(16) ushort_t As[2][128][40];
  int tid  = threadIdx.x;
  int lane = tid & 63;
  int wave = tid >> 6;
  int wr = wave >> 1, wc = wave & 1;
  int quad = lane >> 4;
  int l15  = lane & 15;
  int r0 = blockIdx.x * 128;
  int cb = blockIdx.y;

  uint4 bfr[4][8];
  {
    const uint4* wpb = Wp + (size_t)(cb*2 + wc) * 2048;
    #pragma unroll
    for (int ct = 0; ct < 4; ct++)
      #pragma unroll
      for (int q = 0; q < 8; q++)
        bfr[ct][q] = wpb[(ct*8 + q)*64 + lane];
  }

  f32x4 acc[4][4];
  #pragma unroll
  for (int rt = 0; rt < 4; rt++)
    #pragma unroll
    for (int ct = 0; ct < 4; ct++)
      acc[rt][ct] = f32x4{0.f, 0.f, 0.f, 0.f};

  int srow = tid >> 1;
  int shalf = tid & 1;
  int grow = min(r0 + srow, N - 1);

  auto load_stage = [&](int it, uint4& v0, uint4& v1){
    int k0 = it*32 + shalf*16;
    if constexpr (A_BF16){
      const ushort_t* Ab = (const ushort_t*)Ap;
      const uint4* ga = (const uint4*)(Ab + (size_t)grow*256 + k0);
      v0 = ga[0]; v1 = ga[1];
    } else {
      const float* Af = (const float*)Ap;
      const float4* ga = (const float4*)(Af + (size_t)grow*256 + k0);
      float4 f0 = ga[0], f1 = ga[1], f2 = ga[2], f3 = ga[3];
      v0.x = pk2bf(f0.x, f0.y); v0.y = pk2bf(f0.z, f0.w);
      v0.z = pk2bf(f1.x, f1.y); v0.w = pk2bf(f1.z, f1.w);
      v1.x = pk2bf(f2.x, f2.y); v1.y = pk2bf(f2.z, f2.w);
      v1.z = pk2bf(f3.x, f3.y); v1.w = pk2bf(f3.z, f3.w);
    }
  };
  auto write_stage = [&](int b, uint4 v0, uint4 v1){
    *(uint4*)&As[b][srow][shalf*16]     = v0;
    *(uint4*)&As[b][srow][shalf*16 + 8] = v1;
  };

  {
    uint4 v0, v1;
    load_stage(0, v0, v1);
    write_stage(0, v0, v1);
  }
  __syncthreads();

  #pragma unroll
  for (int it = 0; it < 8; it++){
    const int b = it & 1;
    uint4 n0, n1;
    if (it < 7) load_stage(it + 1, n0, n1);
    #pragma unroll
    for (int rt = 0; rt < 4; rt++){
      int arow = wr*64 + rt*16 + l15;
      uint4 av = *(const uint4*)&As[b][arow][quad*8];
      bf16x8 af = as_bf16x8(av);
      #pragma unroll
      for (int ct = 0; ct < 4; ct++)
        acc[rt][ct] = __builtin_amdgcn_mfma_f32_16x16x32_bf16(
            af, as_bf16x8(bfr[ct][it]), acc[rt][ct], 0, 0, 0);
    }
    if (it < 7){
      write_stage(b ^ 1, n0, n1);
      __syncthreads();
    }
  }

  // store C (fp8): row = r0+wr*64+rt*16+quad*4+g, col = cb*128+wc*64+ct*16+l15
  int crow0 = r0 + wr*64 + quad*4;
  int ccol0 = cb*128 + wc*64 + l15;
  #pragma unroll
  for (int rt = 0; rt < 4; rt++){
    #pragma unroll
    for (int g = 0; g < 4; g++){
      int row = crow0 + rt*16 + g;
      if (row < N){
        #pragma unroll
        for (int ct = 0; ct < 4; ct++)
          out[(size_t)row*256 + ccol0 + ct*16] = f2fp8(acc[rt][ct][g]);
      }
    }
  }
}

// ---------- GCN aggregation (fp8 gather -> bf16 out): half-wave (32 lanes) per
// node, 8 fp8 cols per lane as one 8B uint2 load (256B/row, fully coalesced).
// Edge loop unrolled x4: 4 independent 256B gathers in flight per half-wave.

__device__ inline void acc_row8(uint2 v, float cc, float* acc){
  float v0,v1,v2,v3,v4,v5,v6,v7;
  fp8x4_to_f32(v.x, v0, v1, v2, v3);
  fp8x4_to_f32(v.y, v4, v5, v6, v7);
  acc[0] = fmaf(v0, cc, acc[0]);
  acc[1] = fmaf(v1, cc, acc[1]);
  acc[2] = fmaf(v2, cc, acc[2]);
  acc[3] = fmaf(v3, cc, acc[3]);
  acc[4] = fmaf(v4, cc, acc[4]);
  acc[5] = fmaf(v5, cc, acc[5]);
  acc[6] = fmaf(v6, cc, acc[6]);
  acc[7] = fmaf(v7, cc, acc[7]);
}

__global__ __launch_bounds__(256) void agg_kernel(const unsigned char* __restrict__ xw,
                                                  const float* __restrict__ dis,
                                                  const int* __restrict__ rp,
                                                  const int* __restrict__ csrc,
                                                  const float* __restrict__ bias,
                                                  ushort_t* __restrict__ out, int N){
  int node = blockIdx.x*8 + (threadIdx.x >> 5);
  int lane = threadIdx.x & 31;
  if (node >= N) return;
  const uint2* xw2 = (const uint2*)xw;     // 8 B = 8 fp8; row = 32 uint2
  float di = dis[node];
  float sc = di * di;
  float acc[8];
  {
    uint2 a = xw2[(size_t)node*32 + lane];
    float v0,v1,v2,v3,v4,v5,v6,v7;
    fp8x4_to_f32(a.x, v0, v1, v2, v3);
    fp8x4_to_f32(a.y, v4, v5, v6, v7);
    acc[0]=v0*sc; acc[1]=v1*sc; acc[2]=v2*sc; acc[3]=v3*sc;
    acc[4]=v4*sc; acc[5]=v5*sc; acc[6]=v6*sc; acc[7]=v7*sc;
  }
  int e0 = rp[node], e1 = rp[node+1];
  int e = e0;
  for (; e + 4 <= e1; e += 4){
    int s0 = csrc[e], s1 = csrc[e+1], s2 = csrc[e+2], s3 = csrc[e+3];
    float c0 = dis[s0]*di, c1 = dis[s1]*di, c2 = dis[s2]*di, c3 = dis[s3]*di;
    uint2 v0 = xw2[(size_t)s0*32 + lane];
    uint2 v1 = xw2[(size_t)s1*32 + lane];
    uint2 v2 = xw2[(size_t)s2*32 + lane];
    uint2 v3 = xw2[(size_t)s3*32 + lane];
    acc_row8(v0, c0, acc);
    acc_row8(v1, c1, acc);
    acc_row8(v2, c2, acc);
    acc_row8(v3, c3, acc);
  }
  for (; e < e1; e++){
    int s = csrc[e];
    float cc = dis[s] * di;
    uint2 v = xw2[(size_t)s*32 + lane];
    acc_row8(v, cc, acc);
  }
  const float4* b4 = (const float4*)bias;   // cols lane*8..lane*8+7
  float4 bA = b4[lane*2], bB = b4[lane*2+1];
  acc[0] = fmaxf(acc[0] + bA.x, 0.f);
  acc[1] = fmaxf(acc[1] + bA.y, 0.f);
  acc[2] = fmaxf(acc[2] + bA.z, 0.f);
  acc[3] = fmaxf(acc[3] + bA.w, 0.f);
  acc[4] = fmaxf(acc[4] + bB.x, 0.f);
  acc[5] = fmaxf(acc[5] + bB.y, 0.f);
  acc[6] = fmaxf(acc[6] + bB.z, 0.f);
  acc[7] = fmaxf(acc[7] + bB.w, 0.f);
  uint4 o;
  o.x = pk2bf(acc[0], acc[1]);
  o.y = pk2bf(acc[2], acc[3]);
  o.z = pk2bf(acc[4], acc[5]);
  o.w = pk2bf(acc[6], acc[7]);
  ((uint4*)out)[(size_t)node*32 + lane] = o;
}

// ---------- mean pool (bf16 input, fp32 accumulate) ----------

__global__ void pool_kernel(const ushort_t* __restrict__ h, const int* __restrict__ ptr,
                            float* __restrict__ hp){
  int t = blockIdx.x; int part = blockIdx.y; int c = threadIdx.x;
  int s0 = ptr[t], s1 = ptr[t+1];
  int len = s1 - s0;
  int chunk = (len + 7) / 8;
  int r0 = s0 + part*chunk;
  int r1 = min(r0 + chunk, s1);
  float acc = 0.f;
  for (int r = r0; r < r1; r++) acc += bf2f(h[(size_t)r*256 + c]);
  if (r1 > r0) atomicAdd(&hp[t*256 + c], acc);
}

// ---------- GX[t,g] = dot(hp[t]/cnt[t], w_ih[g]) + b_ih[g] (+ b_hh[g] for r,z
// gates, folded here so the GRU loop carries 2 fewer live VGPRs) ----------

__global__ __launch_bounds__(768) void gx_kernel(const float* __restrict__ hp,
                                                 const int* __restrict__ ptr,
                                                 const float* __restrict__ wih,
                                                 const float* __restrict__ bih,
                                                 const float* __restrict__ bhh,
                                                 float* __restrict__ gx){
  __shared__ float xs[256];
  int t = blockIdx.x; int g = threadIdx.x;
  if (g < 256){
    float cf = (float)max(ptr[t+1] - ptr[t], 1);
    xs[g] = hp[t*256 + g] / cf;
  }
  __syncthreads();
  float acc = bih[g] + (g < 512 ? bhh[g] : 0.f);
  const float* wr = wih + (size_t)g*256;
  #pragma unroll 4
  for (int k = 0; k < 256; k++) acc = fmaf(xs[k], wr[k], acc);
  gx[t*768 + g] = acc;
}

// ---------- sequential GRU: single block, 512 threads (2 threads/gate).
// r7 POST-MORTEM: VGPR_Count=92 with 88 "register-tier" VGPRs declared and
// WRITE_SIZE=0 -> the compiler SANK the preamble weight loads into the loop
// (legal rematerialization of const loads) and re-streamed 180KB/step from
// L2: 244KB/step / 64B/cy = 3900cy = 1.6us/step, matching the measured 90us.
// FIX: (a) pin 20 uint4 (80 VGPRs) with asm volatile "+v" -- opaque defs the
// allocator cannot rematerialize; (b) stream the last 2 uint4 of the REG
// region (z c2, words 20/21 -- layout-compatible) per step; (c) rolling
// 4-slot stream staging (16 regs in flight, refill-after-consume).
// Budget: 80 pinned + 16 staging + 6 acc + 8 h + ~15 misc ~= 125 <= 128 cap.
// Per-step: LDS 147KB/128B/cy ~1150cy || stream 80KB/64B/cy ~1280cy || VALU.
// (r8 bench was an infra container failure; this is the r8 kernel re-run.)

__device__ inline float fast_sig(float x){
  return __builtin_amdgcn_rcpf(1.f + __expf(-x));
}
__device__ inline float fast_tanh(float x){
  // 1 - 2/(e^{2x}+1); exact limits at +-inf via rcp(inf)=0
  return 1.f - 2.f*__builtin_amdgcn_rcpf(1.f + __expf(2.f*x));
}

__global__ __launch_bounds__(512, 1) void gru_kernel(const float* __restrict__ gx,
                                                     const unsigned* __restrict__ whhp,
                                                     const float* __restrict__ bhh,
                                                     const float* __restrict__ Wc,
                                                     const float* __restrict__ bc,
                                                     float* __restrict__ out){
  __shared__ uint2 lw2[36*512];                  // 147456 B weight tier
  __shared__ __align__(16) _Float16 hh[2][256];  // 1 KB, double-buffered h
  __shared__ float hfin[256];                    // 1 KB
  int tid = threadIdx.x;
  int i = tid >> 1;        // gate index 0..255
  int half = tid & 1;      // k-half

  // LDS tier: cooperative linear copy (FIRST, so its transient regs don't
  // collide with the pinned tier)
  {
    const uint2* Lz2 = (const uint2*)(whhp + WHHP_LBASE);
    #pragma unroll
    for (int r = 0; r < 36; r++) lw2[r*512 + tid] = Lz2[r*512 + tid];
  }

  // pinned register tier: 20 coalesced uint4 loads (r all + z c0..1),
  // then opaque-pin so the allocator cannot sink/rematerialize them.
  uint4 wreg4[20];
  const uint4* R4 = (const uint4*)whhp;
  {
    #pragma unroll
    for (int j = 0; j < 20; j++) wreg4[j] = R4[j*512 + tid];
  }
  #pragma unroll
  for (int j = 0; j < 20; j++)
    asm volatile("" : "+v"(wreg4[j].x), "+v"(wreg4[j].y),
                      "+v"(wreg4[j].z), "+v"(wreg4[j].w));

  float bN = bhh[i + 512];           // r,z biases folded into gx upstream
  if (tid < 256) hh[0][tid] = (_Float16)0.f;
  float h = 0.f;
  __syncthreads();

  #pragma unroll 1
  for (int t = 0; t < 64; t++){
    const float* gxt = gx + (size_t)t*768;
    float gxr = gxt[i], gxz = gxt[256 + i], gxn = gxt[512 + i];
    const uint4* hh4 = (const uint4*)((const char*)hh + ((t & 1) << 9) + (half << 8));
    const uint4* S4 = (const uint4*)(whhp + WHHP_SBASE + ((unsigned)(t & 1))*WHHP_SREP);
    // rolling 4-slot stream staging: sA pair / sB pair, refill after consume
    uint4 sA0 = R4[20*512 + tid];   // z c2 (slots 80..83)
    uint4 sA1 = R4[21*512 + tid];   // z c2 (slots 84..87)
    uint4 sB0 = S4[0*512 + tid];    // n c4 a
    uint4 sB1 = S4[1*512 + tid];    // n c4 b
    float aR0=0.f, aR1=0.f, aZ0=0.f, aZ1=0.f, aN0=0.f, aN1=0.f;
    #pragma unroll
    for (int c = 0; c < 8; c++){
      uint4 hA = hh4[c*2], hB = hh4[c*2 + 1];
      h2_t h0=u2h2(hA.x), h1=u2h2(hA.y), h2v=u2h2(hA.z), h3=u2h2(hA.w);
      h2_t h4=u2h2(hB.x), h5=u2h2(hB.y), h6v=u2h2(hB.z), h7=u2h2(hB.w);
      // ---- r gate: pinned regs words 2c, 2c+1 ----
      {
        uint4 wa = wreg4[c*2], wb = wreg4[c*2 + 1];
        aR0 = fdot2a(h0,  u2h2(wa.x), aR0); aR1 = fdot2a(h1, u2h2(wa.y), aR1);
        aR0 = fdot2a(h2v, u2h2(wa.z), aR0); aR1 = fdot2a(h3, u2h2(wa.w), aR1);
        aR0 = fdot2a(h4,  u2h2(wb.x), aR0); aR1 = fdot2a(h5, u2h2(wb.y), aR1);
        aR0 = fdot2a(h6v, u2h2(wb.z), aR0); aR1 = fdot2a(h7, u2h2(wb.w), aR1);
      }
      // ---- z gate: c0..1 pinned (words 16..19), c2 streamed, c3..7 LDS ----
      if (c < 2){
        uint4 za = wreg4[16 + c*2], zb = wreg4[17 + c*2];
        aZ0 = fdot2a(h0,  u2h2(za.x), aZ0); aZ1 = fdot2a(h1, u2h2(za.y), aZ1);
        aZ0 = fdot2a(h2v, u2h2(za.z), aZ0); aZ1 = fdot2a(h3, u2h2(za.w), aZ1);
        aZ0 = fdot2a(h4,  u2h2(zb.x), aZ0); aZ1 = fdot2a(h5, u2h2(zb.y), aZ1);
        aZ0 = fdot2a(h6v, u2h2(zb.z), aZ0); aZ1 = fdot2a(h7, u2h2(zb.w), aZ1);
      } else if (c == 2){
        aZ0 = fdot2a(h0,  u2h2(sA0.x), aZ0); aZ1 = fdot2a(h1, u2h2(sA0.y), aZ1);
        aZ0 = fdot2a(h2v, u2h2(sA0.z), aZ0); aZ1 = fdot2a(h3, u2h2(sA0.w), aZ1);
        aZ0 = fdot2a(h4,  u2h2(sA1.x), aZ0); aZ1 = fdot2a(h5, u2h2(sA1.y), aZ1);
        aZ0 = fdot2a(h6v, u2h2(sA1.z), aZ0); aZ1 = fdot2a(h7, u2h2(sA1.w), aZ1);
        sA0 = S4[2*512 + tid];   // refill: n c5
        sA1 = S4[3*512 + tid];
      } else {
        int pb = (c - 3)*4;
        uint2 z0 = lw2[(pb+0)*512 + tid], z1 = lw2[(pb+1)*512 + tid];
        uint2 z2 = lw2[(pb+2)*512 + tid], z3 = lw2[(pb+3)*512 + tid];
        aZ0 = fdot2a(h0,  u2h2(z0.x), aZ0); aZ1 = fdot2a(h1, u2h2(z0.y), aZ1);
        aZ0 = fdot2a(h2v, u2h2(z1.x), aZ0); aZ1 = fdot2a(h3, u2h2(z1.y), aZ1);
        aZ0 = fdot2a(h4,  u2h2(z2.x), aZ0); aZ1 = fdot2a(h5, u2h2(z2.y), aZ1);
        aZ0 = fdot2a(h6v, u2h2(z3.x), aZ0); aZ1 = fdot2a(h7, u2h2(z3.y), aZ1);
      }
      // ---- n gate: c0..3 LDS (pairs 20+), c4..7 streamed w/ rolling refill ----
      if (c < 4){
        int pb = 20 + c*4;
        uint2 n0 = lw2[(pb+0)*512 + tid], n1 = lw2[(pb+1)*512 + tid];
        uint2 n2 = lw2[(pb+2)*512 + tid], n3 = lw2[(pb+3)*512 + tid];
        aN0 = fdot2a(h0,  u2h2(n0.x), aN0); aN1 = fdot2a(h1, u2h2(n0.y), aN1);
        aN0 = fdot2a(h2v, u2h2(n1.x), aN0); aN1 = fdot2a(h3, u2h2(n1.y), aN1);
        aN0 = fdot2a(h4,  u2h2(n2.x), aN0); aN1 = fdot2a(h5, u2h2(n2.y), aN1);
        aN0 = fdot2a(h6v, u2h2(n3.x), aN0); aN1 = fdot2a(h7, u2h2(n3.y), aN1);
      } else {
        uint4 na = (c & 1) ? sA0 : sB0;
        uint4 nb = (c & 1) ? sA1 : sB1;
        aN0 = fdot2a(h0,  u2h2(na.x), aN0); aN1 = fdot2a(h1, u2h2(na.y), aN1);
        aN0 = fdot2a(h2v, u2h2(na.z), aN0); aN1 = fdot2a(h3, u2h2(na.w), aN1);
        aN0 = fdot2a(h4,  u2h2(nb.x), aN0); aN1 = fdot2a(h5, u2h2(nb.y), aN1);
        aN0 = fdot2a(h6v, u2h2(nb.z), aN0); aN1 = fdot2a(h7, u2h2(nb.w), aN1);
        if (c == 4){ sB0 = S4[4*512 + tid]; sB1 = S4[5*512 + tid]; }   // n c6
        if (c == 5){ sA0 = S4[6*512 + tid]; sA1 = S4[7*512 + tid]; }   // n c7
      }
    }
    float accR = aR0 + aR1, accZ = aZ0 + aZ1, accN = aN0 + aN1;
    accR += __shfl_xor(accR, 1);
    accZ += __shfl_xor(accZ, 1);
    accN += __shfl_xor(accN, 1);
    float r = fast_sig(gxr + accR);
    float z = fast_sig(gxz + accZ);
    float n = fast_tanh(gxn + r*(accN + bN));
    float hnew = (1.f - z)*n + z*h;
    if (half == 0) hh[(t & 1) ^ 1][i] = (_Float16)hnew;
    h = hnew;
    __syncthreads();
  }

  if (half == 0) hfin[i] = h;
  __syncthreads();
  if (tid < 64){
    int r = tid >> 2, qq = tid & 3;
    const float4* wrow = (const float4*)(Wc + (size_t)r*256 + (size_t)qq*64);
    const float4* hv = (const float4*)(hfin + (size_t)qq*64);
    float acc = 0.f;
    #pragma unroll
    for (int k = 0; k < 16; k++){
      float4 wv = wrow[k];
      float4 xv = hv[k];
      acc = fmaf(wv.x, xv.x, acc);
      acc = fmaf(wv.y, xv.y, acc);
      acc = fmaf(wv.z, xv.z, acc);
      acc = fmaf(wv.w, xv.w, acc);
    }
    acc += __shfl_xor(acc, 1);
    acc += __shfl_xor(acc, 2);
    if (qq == 0) out[r] = acc + bc[r];
  }
}

extern "C" void kernel_launch(void* const* d_in, const int* in_sizes, int n_in,
                              void* d_out, int out_size, void* d_ws, size_t ws_size,
                              hipStream_t stream){
  const float* x   = (const float*)d_in[0];
  const int*   ei  = (const int*)d_in[1];
  const int*   ptr = (const int*)d_in[2];
  const float* W1  = (const float*)d_in[3];
  const float* b1  = (const float*)d_in[4];
  const float* W2  = (const float*)d_in[5];
  const float* b2  = (const float*)d_in[6];
  const float* wih = (const float*)d_in[7];
  const float* whh = (const float*)d_in[8];
  const float* bih = (const float*)d_in[9];
  const float* bhh = (const float*)d_in[10];
  const float* Wc  = (const float*)d_in[11];
  const float* bc  = (const float*)d_in[12];
  float* outp = (float*)d_out;

  const int N = in_sizes[0] / 256;   // 100000
  const int E = in_sizes[1] / 2;     // 1600000

  char* w = (char*)d_ws;
  size_t off = 0;
  auto alloc = [&](size_t bytes){ void* p = w + off; off = align512(off + bytes); return p; };
  unsigned char* bufA = (unsigned char*)alloc((size_t)N*256);     // xw (fp8 e4m3)
  ushort_t*      bufB = (ushort_t*)alloc((size_t)N*256*2);        // h  (bf16)
  float* dis  = (float*)alloc((size_t)N*4);
  int*   cnt  = (int*)  alloc((size_t)N*4);
  int*   rp   = (int*)  alloc((size_t)(N+1)*4);
  int*   bsum = (int*)  alloc(128*4);
  int*   csrc = (int*)  alloc((size_t)E*4);
  uint4* Wp1  = (uint4*)alloc(8192*16);
  uint4* Wp2  = (uint4*)alloc(8192*16);
  unsigned* whhp = (unsigned*)alloc((size_t)WHHP_TOTAL*4);        // GRU 3-tier weights
  float* hp   = (float*)alloc((size_t)64*256*4);
  float* gxb  = (float*)alloc((size_t)64*768*4);
  (void)ws_size; (void)n_in; (void)out_size;

  hipMemsetAsync(cnt, 0, (size_t)N*4, stream);
  hipMemsetAsync(hp,  0, (size_t)64*256*4, stream);

  // CSR build + degree + weight packing
  count_kernel<<<(E+255)/256, 256, 0, stream>>>(ei, cnt, E);
  dis_kernel<<<(N+255)/256, 256, 0, stream>>>(cnt, dis, N);
  int nb = (N + 1023) / 1024;
  scan_block_kernel<<<nb, 1024, 0, stream>>>(cnt, rp, bsum, N);
  scan_sums_kernel<<<1, 128, 0, stream>>>(bsum, nb);
  add_off_kernel<<<(N+255)/256, 256, 0, stream>>>(rp, bsum, cnt, N);
  int fnb = (E + 255) / 256;
  fill_kernel<<<fnb*FILL_P, 256, 0, stream>>>(ei, rp, cnt, csrc, E, N);
  packW_kernel<<<32, 256, 0, stream>>>(W1, Wp1);
  packW_kernel<<<32, 256, 0, stream>>>(W2, Wp2);
  packWhh_kernel<<<384, 256, 0, stream>>>(whh, whhp);

  // GCN layer 1
  gemm_mfma<false><<<dim3((N+127)/128, 2), 256, 0, stream>>>(x, Wp1, bufA, N);
  agg_kernel<<<(N+7)/8, 256, 0, stream>>>(bufA, dis, rp, csrc, b1, bufB, N);
  // GCN layer 2
  gemm_mfma<true><<<dim3((N+127)/128, 2), 256, 0, stream>>>(bufB, Wp2, bufA, N);
  agg_kernel<<<(N+7)/8, 256, 0, stream>>>(bufA, dis, rp, csrc, b2, bufB, N);

  // pool + GRU + classifier
  pool_kernel<<<dim3(64, 8), 256, 0, stream>>>(bufB, ptr, hp);
  gx_kernel<<<64, 768, 0, stream>>>(hp, ptr, wih, bih, bhh, gxb);
  gru_kernel<<<1, 512, 0, stream>>>(gxb, whhp, bhh, Wc, bc, outp);
}